// Round 7
// baseline (242.175 us; speedup 1.0000x reference)
//
#include <hip/hip_runtime.h>

// DCE-MRI eTofts forward model — R4 champion structure, cache-retaining
// (non-nt) loads/stores. Single-variable A/B vs R4 (72 us rocprof).
// param: [B,3] f32, T10: [B,1] f32, cp: [B,T] f32  ->  out: [B,T] f32
//
// Working set cp(117MB) + out(117MB) + param/T10(4MB) ~= 238 MB fits the
// 256 MB Infinity Cache; the bench runs many iterations back-to-back and
// R4's FETCH=88MB < cp's 117MB proves partial cross-iteration L3 residency.
// All prior rounds used __builtin_nontemporal_* hints — explicitly telling
// the cache NOT to retain the one working set that fits. This round: plain
// loads/stores, everything else byte-identical to R4.
//
// Structure recap (R4, 72 us): block = 128 threads = 2 autonomous waves;
// each wave owns 64 rows + a PRIVATE LDS region; NO barriers (intra-wave DS
// ordering is in-order within a wave; R3-R6 all passed barrier-free).
// T tiled 7 x 16 (one aligned 64 B line per row-tile). LDS transposed
// [t][row], stride LP=66: compute access bank (2t+l)%32 and stage/store
// access both exactly 2 lanes/bank = conflict-free (verified 0 in R3/R4/R6).
// All 28 row-loads written up-front; compiler batches them (VGPR=64) into
// its own near-optimal pipeline — R6 proved hand double-buffering only
// makes it worse (compiler sinks the loads, VGPR 36, 84 us).

typedef float f32x4 __attribute__((ext_vector_type(4)));

static constexpr int   Bn    = 262144;
static constexpr int   Tn    = 112;
static constexpr int   TT    = 16;         // timesteps per tile (64 B per row-tile)
static constexpr int   NT    = Tn / TT;    // 7 tiles
static constexpr int   LP    = 66;         // LDS word stride between t-rows
static constexpr float TRc   = 0.005f;
static constexpr float DELTT = 0.075f;                 // 4.5/60
static constexpr float R1R   = 4.5f;
static constexpr float SIN_A = 0.25881904510252074f;   // sin(15 deg)
static constexpr float COS_A = 0.9659258262890683f;    // cos(15 deg)

__global__ __launch_bounds__(128) void etofts_kernel(
    const float* __restrict__ param,
    const float* __restrict__ T10,
    const float* __restrict__ cp,
    float* __restrict__ out)
{
    __shared__ float lds[2][TT * LP];      // 2 x 4224 B = 8448 B per WG

    const int tid = threadIdx.x;
    const int w   = tid >> 6;              // wave id within block
    const int l   = tid & 63;              // lane
    float* __restrict__ sl = lds[w];       // wave-private LDS region

    const int b0 = blockIdx.x * 128 + w * 64;  // this wave's first row
    const int b  = b0 + l;                     // this lane's own row

    // Per-lane mapping: row = i*16 + (l>>2), c4 = l&3; each 4-lane group
    // covers one contiguous aligned 64 B line.
    const int rsub = l >> 2;               // 0..15
    const int c4   = l & 3;                // 0..3
    const int tb   = c4 * 4;               // first timestep of this float4

    // ---- issue ALL row loads up front (compiler batches/paces them) ----
    f32x4 r[NT * 4];
    #pragma unroll
    for (int k = 0; k < NT; ++k) {         // tile-major: oldest = tile 0
        #pragma unroll
        for (int i = 0; i < 4; ++i) {
            const int row = i * 16 + rsub;
            r[k * 4 + i] = *(const f32x4*)(cp + (size_t)(b0 + row) * Tn
                                           + k * TT + c4 * 4);
        }
    }

    // Parameter scaling + clamping
    const float ktrans = fminf(fmaxf(param[3 * b + 0] * 0.2f, 1e-5f), 0.2f);
    const float vp     = fminf(fmaxf(param[3 * b + 1] * 0.1f, 0.0005f), 0.1f);
    const float ve     = fminf(fmaxf(param[3 * b + 2] * 0.6f, 0.04f), 0.6f);
    const float decay  = __expf(-(ktrans / ve) * DELTT);
    const float r10    = 1.0f / T10[b];

    float c = 0.0f;                        // IIR state across tiles

    #pragma unroll
    for (int tile = 0; tile < NT; ++tile) {
        // ---- stage this tile's registers into transposed LDS ----
        #pragma unroll
        for (int i = 0; i < 4; ++i) {
            const int row = i * 16 + rsub;
            const f32x4 v = r[tile * 4 + i];
            sl[(tb + 0) * LP + row] = v.x;
            sl[(tb + 1) * LP + row] = v.y;
            sl[(tb + 2) * LP + row] = v.z;
            sl[(tb + 3) * LP + row] = v.w;
        }
        // (no barrier: wave-private LDS; DS pipe is in-order within a wave)

        // ---- compute 16 steps in place (own column: no cross-lane race) ----
        #pragma unroll
        for (int t = 0; t < TT; ++t) {
            const float cpt = sl[t * LP + l];
            c = fmaf(c, decay, cpt * DELTT);             // IIR recurrence
            const float ct = fmaf(c, ktrans, vp * cpt);  // vp*cp + ce
            const float E  = __expf(-TRc * fmaf(R1R, ct, r10));
            sl[t * LP + l] = __fdividef((1.0f - E) * (SIN_A * 20.0f),
                                        fmaf(-E, COS_A, 1.0f));
        }

        // ---- coalesced full-line store from transposed LDS ----
        #pragma unroll
        for (int i = 0; i < 4; ++i) {
            const int row = i * 16 + rsub;
            f32x4 o;
            o.x = sl[(tb + 0) * LP + row];
            o.y = sl[(tb + 1) * LP + row];
            o.z = sl[(tb + 2) * LP + row];
            o.w = sl[(tb + 3) * LP + row];
            *(f32x4*)(out + (size_t)(b0 + row) * Tn + tile * TT + c4 * 4) = o;
        }
        // (no barrier: next stage's ds_writes are WAR-ordered by the in-order
        //  DS pipe within the wave)
    }
}

extern "C" void kernel_launch(void* const* d_in, const int* in_sizes, int n_in,
                              void* d_out, int out_size, void* d_ws, size_t ws_size,
                              hipStream_t stream) {
    const float* param = (const float*)d_in[0];
    const float* T10   = (const float*)d_in[1];
    const float* cp    = (const float*)d_in[2];
    float*       out   = (float*)d_out;

    const int threads = 128;
    const int blocks  = Bn / 128;          // 2048 two-wave workgroups
    etofts_kernel<<<blocks, threads, 0, stream>>>(param, T10, cp, out);
}

// Round 8
// 233.936 us; speedup vs baseline: 1.0352x; 1.0352x over previous
//
#include <hip/hip_runtime.h>

// DCE-MRI eTofts forward model — R4 structure + depth-4 load pipeline pinned
// with sched_barrier so the compiler cannot sink the loads (R6 lesson).
// param: [B,3] f32, T10: [B,1] f32, cp: [B,T] f32  ->  out: [B,T] f32
//
// Champion config recap (R4 = 72 us): 128 threads = 2 autonomous waves, each
// owns 64 rows + PRIVATE LDS, no barriers; T tiled 7 x 16 (one aligned 64 B
// line per row-tile); LDS transposed [t][row] stride LP=66 (all phases
// exactly 2 lanes/bank — verified 0 conflicts); nontemporal loads AND stores
// (R7 proved plain loads/stores collapse achieved BW 3.1 -> 2.1 TB/s).
//
// R4's limiter (outstanding-bytes model): compiler chose VGPR=64 => only
// ~8-11 float4 loads in flight/wave => ~2.5 KB demand/CU => ~3 TB/s at
// ~350 ns mean latency. This version forces depth-4: r[4][4] buffers
// (64 payload VGPRs), prologue issues 16 loads + sched_barrier(0) (nothing
// may cross), each tile refills its buffer 4 tiles ahead + sched_barrier(0).
// Target VGPR 95-128: stays at 4 waves/SIMD so all 16 waves/CU co-resident.

typedef float f32x4 __attribute__((ext_vector_type(4)));

static constexpr int   Bn    = 262144;
static constexpr int   Tn    = 112;
static constexpr int   TT    = 16;         // timesteps per tile (64 B per row-tile)
static constexpr int   NT    = Tn / TT;    // 7 tiles
static constexpr int   LP    = 66;         // LDS word stride between t-rows
static constexpr float TRc   = 0.005f;
static constexpr float DELTT = 0.075f;                 // 4.5/60
static constexpr float R1R   = 4.5f;
static constexpr float SIN_A = 0.25881904510252074f;   // sin(15 deg)
static constexpr float COS_A = 0.9659258262890683f;    // cos(15 deg)

__global__ __launch_bounds__(128, 4) void etofts_kernel(
    const float* __restrict__ param,
    const float* __restrict__ T10,
    const float* __restrict__ cp,
    float* __restrict__ out)
{
    __shared__ float lds[2][TT * LP];      // 2 x 4224 B = 8448 B per WG

    const int tid = threadIdx.x;
    const int w   = tid >> 6;              // wave id within block
    const int l   = tid & 63;              // lane
    float* __restrict__ sl = lds[w];       // wave-private LDS region

    const int b0 = blockIdx.x * 128 + w * 64;  // this wave's first row
    const int b  = b0 + l;                     // this lane's own row

    // Per-lane mapping: row = i*16 + (l>>2), c4 = l&3; each 4-lane group
    // covers one contiguous aligned 64 B line.
    const int rsub = l >> 2;               // 0..15
    const int c4   = l & 3;                // 0..3
    const int tb   = c4 * 4;               // first timestep of this float4

    // ---- prologue: issue tiles 0..3 (16 float4 = 64 payload VGPRs) ----
    f32x4 r[4][4];
    #pragma unroll
    for (int k = 0; k < 4; ++k) {
        #pragma unroll
        for (int i = 0; i < 4; ++i) {
            const int row = i * 16 + rsub;
            r[k][i] = __builtin_nontemporal_load(
                (const f32x4*)(cp + (size_t)(b0 + row) * Tn + k * TT + c4 * 4));
        }
    }
    // Nothing may cross: the 16 loads are issued HERE, results stay live.
    __builtin_amdgcn_sched_barrier(0);

    // Parameter scaling + clamping
    const float ktrans = fminf(fmaxf(param[3 * b + 0] * 0.2f, 1e-5f), 0.2f);
    const float vp     = fminf(fmaxf(param[3 * b + 1] * 0.1f, 0.0005f), 0.1f);
    const float ve     = fminf(fmaxf(param[3 * b + 2] * 0.6f, 0.04f), 0.6f);
    const float decay  = __expf(-(ktrans / ve) * DELTT);
    const float r10    = 1.0f / T10[b];

    float c = 0.0f;                        // IIR state across tiles

    #pragma unroll
    for (int tile = 0; tile < NT; ++tile) {
        const int buf = tile & 3;          // compile-time after full unroll

        // ---- stage tile `tile` into transposed LDS ----
        // (compiler emits a counted vmcnt targeting the 4 OLDEST loads)
        #pragma unroll
        for (int i = 0; i < 4; ++i) {
            const int row = i * 16 + rsub;
            const f32x4 v = r[buf][i];
            sl[(tb + 0) * LP + row] = v.x;
            sl[(tb + 1) * LP + row] = v.y;
            sl[(tb + 2) * LP + row] = v.z;
            sl[(tb + 3) * LP + row] = v.w;
        }

        // ---- refill this buffer with tile+4 (keep 12-16 loads in flight) ----
        if (tile + 4 < NT) {
            #pragma unroll
            for (int i = 0; i < 4; ++i) {
                const int row = i * 16 + rsub;
                r[buf][i] = __builtin_nontemporal_load(
                    (const f32x4*)(cp + (size_t)(b0 + row) * Tn
                                   + (tile + 4) * TT + c4 * 4));
            }
        }
        // Pin: refill loads are issued BEFORE compute, and cannot sink.
        __builtin_amdgcn_sched_barrier(0);

        // ---- compute 16 steps in place (own column: no cross-lane race) ----
        #pragma unroll
        for (int t = 0; t < TT; ++t) {
            const float cpt = sl[t * LP + l];
            c = fmaf(c, decay, cpt * DELTT);             // IIR recurrence
            const float ct = fmaf(c, ktrans, vp * cpt);  // vp*cp + ce
            const float E  = __expf(-TRc * fmaf(R1R, ct, r10));
            sl[t * LP + l] = __fdividef((1.0f - E) * (SIN_A * 20.0f),
                                        fmaf(-E, COS_A, 1.0f));
        }

        // ---- coalesced full-line nontemporal store ----
        #pragma unroll
        for (int i = 0; i < 4; ++i) {
            const int row = i * 16 + rsub;
            f32x4 o;
            o.x = sl[(tb + 0) * LP + row];
            o.y = sl[(tb + 1) * LP + row];
            o.z = sl[(tb + 2) * LP + row];
            o.w = sl[(tb + 3) * LP + row];
            __builtin_nontemporal_store(
                o, (f32x4*)(out + (size_t)(b0 + row) * Tn + tile * TT + c4 * 4));
        }
        // (no barrier: wave-private LDS; DS pipe is in-order within a wave)
    }
}

extern "C" void kernel_launch(void* const* d_in, const int* in_sizes, int n_in,
                              void* d_out, int out_size, void* d_ws, size_t ws_size,
                              hipStream_t stream) {
    const float* param = (const float*)d_in[0];
    const float* T10   = (const float*)d_in[1];
    const float* cp    = (const float*)d_in[2];
    float*       out   = (float*)d_out;

    const int threads = 128;
    const int blocks  = Bn / 128;          // 2048 two-wave workgroups
    etofts_kernel<<<blocks, threads, 0, stream>>>(param, T10, cp, out);
}